// Round 12
// baseline (215.932 us; speedup 1.0000x reference)
//
#include <hip/hip_runtime.h>
#include <hip/hip_bf16.h>
#include <stdint.h>

#define B_N   16384
#define H_DIM 768
#define HH    384
#define NE    8
#define CSTRIDE 32   // counts padded: one counter per 128B line

typedef __attribute__((ext_vector_type(8))) short bf16x8;
typedef __attribute__((ext_vector_type(4))) float f32x4;

__device__ __forceinline__ unsigned short f2bf(float f) {
    uint32_t u = __float_as_uint(f);
    return (unsigned short)((u + 0x7fffu + ((u >> 16) & 1u)) >> 16);   // RNE
}

// ---------------- routing (two-level: LDS histogram -> padded global counters) ----------------
__global__ void zero_counts_kernel(int* __restrict__ counts) {
    if (threadIdx.x < NE) counts[threadIdx.x * CSTRIDE] = 0;
}

__global__ void route_kernel(const float* __restrict__ logits,
                             int* __restrict__ counts,
                             int* __restrict__ buckets) {
    __shared__ int lcnt[NE];
    __shared__ int lbase[NE];
    const int tid = threadIdx.x;
    if (tid < NE) lcnt[tid] = 0;
    __syncthreads();

    const int b = blockIdx.x * 256 + tid;
    const float* l = logits + (size_t)b * NE;
    float best = l[0];
    int be = 0;
#pragma unroll
    for (int e = 1; e < NE; ++e) {
        float v = l[e];
        if (v > best) { best = v; be = e; }   // strict >: first-index tie-break (jnp.argmax)
    }
    const int lpos = atomicAdd(&lcnt[be], 1);
    __syncthreads();
    if (tid < NE) lbase[tid] = atomicAdd(&counts[tid * CSTRIDE], lcnt[tid]);
    __syncthreads();
    buckets[be * B_N + lbase[be] + lpos] = b;
}

// ---------------- W transpose + bf16 cvt (also zeroes padded counters) ----------------
__global__ void transpose_cvt_kernel(const float* __restrict__ W1,
                                     const float* __restrict__ W2,
                                     unsigned short* __restrict__ W1T,
                                     unsigned short* __restrict__ W2T,
                                     int* __restrict__ counts) {
    if (blockIdx.x == 0 && blockIdx.y == 0 && blockIdx.z == 0 && threadIdx.x < NE)
        counts[threadIdx.x * CSTRIDE] = 0;

    const int z = blockIdx.z;
    const int R = z ? HH : H_DIM;
    const int C = z ? H_DIM : HH;
    const float* src = (z ? W2 : W1) + (size_t)blockIdx.y * R * C;
    unsigned short* dst = (z ? W2T : W1T) + (size_t)blockIdx.y * R * C;

    const int ctiles = C >> 5;
    const int ty = blockIdx.x / ctiles;
    const int tx = blockIdx.x % ctiles;

    __shared__ float Ts[32][33];
    const int lr = threadIdx.x >> 3;
    const int lc = (threadIdx.x & 7) * 4;

    f32x4 v = *reinterpret_cast<const f32x4*>(src + (size_t)(ty * 32 + lr) * C + tx * 32 + lc);
    Ts[lr][lc + 0] = v[0]; Ts[lr][lc + 1] = v[1];
    Ts[lr][lc + 2] = v[2]; Ts[lr][lc + 3] = v[3];
    __syncthreads();

    ushort4 o;
    o.x = f2bf(Ts[lc + 0][lr]);
    o.y = f2bf(Ts[lc + 1][lr]);
    o.z = f2bf(Ts[lc + 2][lr]);
    o.w = f2bf(Ts[lc + 3][lr]);
    *reinterpret_cast<ushort4*>(dst + (size_t)(tx * 32 + lr) * R + ty * 32 + lc) = o;
}

// ---------------- GEMM1: 8 waves, double-buffered LDS, T14 pipeline ----------------
// Tile 64(M) x 128(N), BK=64. 512 thr. Wave (wr,wc) owns 32x32. 1D grid, e = wgid&7.
template<int KTOT, int NTOT, bool A_F32, bool RELU, bool OUTBF>
__global__ __launch_bounds__(512, 6)
void gemm_kernel(const void* __restrict__ Aglob,
                 const unsigned short* __restrict__ WT,   // [NE][NTOT][KTOT] bf16
                 const float* __restrict__ bias,          // [NE][NTOT]
                 const int* __restrict__ counts,
                 const int* __restrict__ buckets,
                 void* __restrict__ Cout) {
    __shared__ __align__(16) unsigned char AsB[2][64 * 128];
    __shared__ __align__(16) unsigned char BsB[2][128 * 128];
    __shared__ int sidx[64];

    const int wgid   = blockIdx.x;
    const int e      = wgid & 7;          // XCD-affine expert
    const int rest   = wgid >> 3;
    const int mtile  = rest & 255;
    const int nchunk = rest >> 8;
    const int cnt    = counts[e * CSTRIDE];
    const int base   = mtile * 64;
    if (base >= cnt) return;
    const int ns  = min(64, cnt - base);
    const int tid = threadIdx.x;

    if (tid < 64) sidx[tid] = buckets[e * B_N + base + (tid < ns ? tid : 0)];
    __syncthreads();

    // staging roles: A 8 thr/row x 8 elts; B 4 thr/row x 16 elts
    const int ar = tid >> 3, aq = tid & 7;
    const int bn = tid >> 2, bq = tid & 3;
    const float*          arow_f = nullptr;
    const unsigned short* arow_h = nullptr;
    if (A_F32) arow_f = (const float*)Aglob + (size_t)sidx[ar] * KTOT + aq * 8;
    else       arow_h = (const unsigned short*)Aglob + (size_t)sidx[ar] * KTOT + aq * 8;
    const unsigned short* brow =
        WT + ((size_t)e * NTOT + nchunk * 128 + bn) * KTOT + bq * 16;

    const int a_slot  = (ar << 7) + ((aq * 16) ^ ((ar & 7) << 4));
    const int b_slot0 = (bn << 7) + (((bq * 32)     ) ^ ((bn & 7) << 4));
    const int b_slot1 = (bn << 7) + (((bq * 32) + 16) ^ ((bn & 7) << 4));

    // wave roles
    const int w = tid >> 6, lane = tid & 63;
    const int wr = w >> 2, wc = w & 3;
    const int fr = lane & 15, fq = lane >> 4;

    f32x4 acc[2][2];
#pragma unroll
    for (int mi = 0; mi < 2; ++mi)
#pragma unroll
        for (int ni = 0; ni < 2; ++ni) acc[mi][ni] = (f32x4)(0.f);

    bf16x8 aReg;
    f32x4  bReg0, bReg1;

    auto LOAD = [&](int k0) {
        if (A_F32) {
            f32x4 f0 = *reinterpret_cast<const f32x4*>(arow_f + k0);
            f32x4 f1 = *reinterpret_cast<const f32x4*>(arow_f + k0 + 4);
            bf16x8 p;
#pragma unroll
            for (int i = 0; i < 4; ++i) {
                p[i]     = (short)f2bf(f0[i]);
                p[i + 4] = (short)f2bf(f1[i]);
            }
            aReg = p;
        } else {
            aReg = *reinterpret_cast<const bf16x8*>(arow_h + k0);
        }
        bReg0 = *reinterpret_cast<const f32x4*>(brow + k0);
        bReg1 = *reinterpret_cast<const f32x4*>(brow + k0 + 8);
    };
    auto WRITE = [&](int buf) {
        *reinterpret_cast<bf16x8*>(&AsB[buf][a_slot])  = aReg;
        *reinterpret_cast<f32x4*>(&BsB[buf][b_slot0]) = bReg0;
        *reinterpret_cast<f32x4*>(&BsB[buf][b_slot1]) = bReg1;
    };
    auto COMPUTE = [&](int buf) {
#pragma unroll
        for (int s = 0; s < 2; ++s) {
            const int kb = s * 64 + fq * 16;
            bf16x8 af[2], bfr[2];
#pragma unroll
            for (int mi = 0; mi < 2; ++mi) {
                int row = wr * 32 + mi * 16 + fr;
                af[mi] = *reinterpret_cast<const bf16x8*>(
                    &AsB[buf][(row << 7) + (kb ^ ((row & 7) << 4))]);
            }
#pragma unroll
            for (int ni = 0; ni < 2; ++ni) {
                int row = wc * 32 + ni * 16 + fr;
                bfr[ni] = *reinterpret_cast<const bf16x8*>(
                    &BsB[buf][(row << 7) + (kb ^ ((row & 7) << 4))]);
            }
#pragma unroll
            for (int mi = 0; mi < 2; ++mi)
#pragma unroll
                for (int ni = 0; ni < 2; ++ni)
                    acc[mi][ni] = __builtin_amdgcn_mfma_f32_16x16x32_bf16(
                        af[mi], bfr[ni], acc[mi][ni], 0, 0, 0);
        }
    };

    LOAD(0);
    WRITE(0);
    __syncthreads();
    int cur = 0;
    for (int k0 = 64; k0 < KTOT; k0 += 64) {
        LOAD(k0);            // issue next-tile global loads early
        COMPUTE(cur);
        WRITE(cur ^ 1);      // vmcnt wait lands here, after compute
        __syncthreads();     // one barrier per K-iter
        cur ^= 1;
    }
    COMPUTE(cur);

    // ---- epilogue ----
    const float* be = bias + (size_t)e * NTOT + nchunk * 128 + wc * 32;
#pragma unroll
    for (int mi = 0; mi < 2; ++mi) {
        const int rl0 = wr * 32 + mi * 16 + fq * 4;
#pragma unroll
        for (int ni = 0; ni < 2; ++ni) {
            const int coll = ni * 16 + fr;
            const int colg = nchunk * 128 + wc * 32 + coll;
            const float bb = be[coll];
#pragma unroll
            for (int r2 = 0; r2 < 4; ++r2) {
                const int rl = rl0 + r2;
                if (rl < ns) {
                    float v = acc[mi][ni][r2] + bb;
                    if (RELU) v = fmaxf(v, 0.f);
                    size_t o = (size_t)sidx[rl] * NTOT + colg;
                    if (OUTBF) ((unsigned short*)Cout)[o] = f2bf(v);
                    else       ((float*)Cout)[o] = v;
                }
            }
        }
    }
}

// ---------------- GEMM2 + norm fused: full-N tile 64x768, BK=32 dbuf, 8 waves ----------------
// Each block owns complete y2 rows -> per-row l2-norm stats computed in-epilogue;
// out = (y2/max(||y2||,1e-6) + x)/max(||.||,1e-12) written directly. No y2 round-trip.
__global__ __launch_bounds__(512, 2)
void gemm2n_kernel(const unsigned short* __restrict__ Hws,   // [B_N][384] bf16
                   const unsigned short* __restrict__ W2T,   // [NE][768][384] bf16
                   const float* __restrict__ b2,             // [NE][768]
                   const float* __restrict__ emb,            // [B_N][768] f32
                   const int* __restrict__ counts,
                   const int* __restrict__ buckets,
                   float* __restrict__ out) {
    __shared__ __align__(16) unsigned char Adb[2][64 * 64];    // 64 rows x 64B (32 bf16)
    __shared__ __align__(16) unsigned char Bdb[2][768 * 64];   // 48KB each
    __shared__ int sidx[64];
    __shared__ float red[3][64][4];
    __shared__ float inv1s[64], inv2s[64];

    const int wgid  = blockIdx.x;
    const int e     = wgid & 7;       // XCD-affine expert
    const int mtile = wgid >> 3;
    const int cnt   = counts[e * CSTRIDE];
    const int base  = mtile * 64;
    if (base >= cnt) return;
    const int ns  = min(64, cnt - base);
    const int tid = threadIdx.x;

    if (tid < 64) sidx[tid] = buckets[e * B_N + base + (tid < ns ? tid : 0)];
    __syncthreads();

    // staging roles: A 8 thr/row x 4 elts (8B); B 1 row/thread (+1 extra for tid<256), 32 elts
    const int ar = tid >> 3, aq = tid & 7;
    const unsigned short* arow = Hws + (size_t)sidx[ar] * HH + aq * 4;
    const int a_slot = (ar << 6) + ((aq * 8) ^ ((ar & 3) << 4));
    const unsigned short* Be = W2T + (size_t)e * H_DIM * HH;

    // wave roles
    const int w = tid >> 6, lane = tid & 63;
    const int wr = w >> 2, wc = w & 3;          // wave tile: rows wr*32..+32, cols wc*192..+192
    const int fr = lane & 15, fq = lane >> 4;

    f32x4 acc[2][12];
#pragma unroll
    for (int mi = 0; mi < 2; ++mi)
#pragma unroll
        for (int ni = 0; ni < 12; ++ni) acc[mi][ni] = (f32x4)(0.f);

    float2 aReg;
    f32x4  bReg0[4], bReg1[4];

    auto LOAD = [&](int k0) {
        aReg = *reinterpret_cast<const float2*>(arow + k0);
        const unsigned short* b0 = Be + (size_t)tid * HH + k0;
#pragma unroll
        for (int j = 0; j < 4; ++j)
            bReg0[j] = *reinterpret_cast<const f32x4*>(b0 + j * 8);
        if (tid < 256) {
            const unsigned short* b1 = Be + (size_t)(tid + 512) * HH + k0;
#pragma unroll
            for (int j = 0; j < 4; ++j)
                bReg1[j] = *reinterpret_cast<const f32x4*>(b1 + j * 8);
        }
    };
    auto WRITE = [&](int buf) {
        *reinterpret_cast<float2*>(&Adb[buf][a_slot]) = aReg;
        const int sw0 = (tid & 3) << 4;
#pragma unroll
        for (int j = 0; j < 4; ++j)
            *reinterpret_cast<f32x4*>(&Bdb[buf][(tid << 6) + ((j * 16) ^ sw0)]) = bReg0[j];
        if (tid < 256) {
            const int r2r = tid + 512;
            const int sw1 = (r2r & 3) << 4;
#pragma unroll
            for (int j = 0; j < 4; ++j)
                *reinterpret_cast<f32x4*>(&Bdb[buf][(r2r << 6) + ((j * 16) ^ sw1)]) = bReg1[j];
        }
    };
    auto COMPUTE = [&](int buf) {
        bf16x8 af[2];
#pragma unroll
        for (int mi = 0; mi < 2; ++mi) {
            int row = wr * 32 + mi * 16 + fr;
            af[mi] = *reinterpret_cast<const bf16x8*>(
                &Adb[buf][(row << 6) + ((fq * 16) ^ ((row & 3) << 4))]);
        }
#pragma unroll
        for (int ni = 0; ni < 12; ++ni) {
            int row = wc * 192 + ni * 16 + fr;
            bf16x8 bfr = *reinterpret_cast<const bf16x8*>(
                &Bdb[buf][(row << 6) + ((fq * 16) ^ ((row & 3) << 4))]);
            acc[0][ni] = __builtin_amdgcn_mfma_f32_16x16x32_bf16(af[0], bfr, acc[0][ni], 0, 0, 0);
            acc[1][ni] = __builtin_amdgcn_mfma_f32_16x16x32_bf16(af[1], bfr, acc[1][ni], 0, 0, 0);
        }
    };

    LOAD(0);
    WRITE(0);
    __syncthreads();
    int cur = 0;
    for (int it = 1; it < HH / 32; ++it) {
        LOAD(it * 32);       // issue next-tile global loads early
        COMPUTE(cur);
        WRITE(cur ^ 1);
        __syncthreads();     // one barrier per K-iter
        cur ^= 1;
    }
    COMPUTE(cur);

    // ---- fused epilogue: bias + per-row norm stats + final write ----
    const float* b2e = b2 + (size_t)e * H_DIM + wc * 192;
    float bb[12];
#pragma unroll
    for (int ni = 0; ni < 12; ++ni) bb[ni] = b2e[ni * 16 + fr];

#pragma unroll
    for (int mi = 0; mi < 2; ++mi) {
#pragma unroll
        for (int r2 = 0; r2 < 4; ++r2) {
            const int grow = wr * 32 + mi * 16 + fq * 4 + r2;
            const float* xrow = emb + (size_t)sidx[grow] * H_DIM + wc * 192;
            float p1 = 0.f, p2 = 0.f, p3 = 0.f;
#pragma unroll
            for (int ni = 0; ni < 12; ++ni) {
                float y = acc[mi][ni][r2] + bb[ni];
                float x = xrow[ni * 16 + fr];
                p1 = fmaf(y, y, p1);
                p2 = fmaf(y, x, p2);
                p3 = fmaf(x, x, p3);
            }
#pragma unroll
            for (int m = 1; m < 16; m <<= 1) {
                p1 += __shfl_xor(p1, m);
                p2 += __shfl_xor(p2, m);
                p3 += __shfl_xor(p3, m);
            }
            if (fr == 0) {
                red[0][grow][wc] = p1;
                red[1][grow][wc] = p2;
                red[2][grow][wc] = p3;
            }
        }
    }
    __syncthreads();
    if (tid < 64) {
        float s1 = red[0][tid][0] + red[0][tid][1] + red[0][tid][2] + red[0][tid][3];
        float s2 = red[1][tid][0] + red[1][tid][1] + red[1][tid][2] + red[1][tid][3];
        float s3 = red[2][tid][0] + red[2][tid][1] + red[2][tid][2] + red[2][tid][3];
        float n1 = fmaxf(sqrtf(s1), 1e-6f);            // EPS_COMBINE
        float i1 = 1.f / n1;
        float t  = s1 * i1 * i1 + 2.f * s2 * i1 + s3;  // ||y2/n1 + x||^2
        float i2 = 1.f / fmaxf(sqrtf(t), 1e-12f);      // EPS_FINAL
        inv1s[tid] = i1;
        inv2s[tid] = i2;
    }
    __syncthreads();
#pragma unroll
    for (int mi = 0; mi < 2; ++mi) {
#pragma unroll
        for (int r2 = 0; r2 < 4; ++r2) {
            const int grow = wr * 32 + mi * 16 + fq * 4 + r2;
            if (grow >= ns) continue;
            const float i1 = inv1s[grow], i2 = inv2s[grow];
            const size_t ro = (size_t)sidx[grow] * H_DIM + wc * 192;
            const float* xrow = emb + ro;
            float* orow = out + ro;
#pragma unroll
            for (int ni = 0; ni < 12; ++ni) {
                float y = acc[mi][ni][r2] + bb[ni];
                float x = xrow[ni * 16 + fr];
                orow[ni * 16 + fr] = (y * i1 + x) * i2;
            }
        }
    }
}

// ---------------- fallback (fp32 fused) if ws too small ----------------
#define TILE 64
#define NTHR 256
#define BK   64
__global__ __launch_bounds__(NTHR, 2)
void moe_fused_fallback(const float* __restrict__ emb,
                        const float* __restrict__ W1,
                        const float* __restrict__ b1,
                        const float* __restrict__ W2,
                        const float* __restrict__ b2,
                        const int* __restrict__ counts,
                        const int* __restrict__ buckets,
                        float* __restrict__ out) {
    __shared__ float Xs[TILE][BK];
    __shared__ __hip_bfloat16 Hs[TILE][HH];
    __shared__ int   sidx[TILE];
    __shared__ float s_in1[TILE];
    __shared__ float s_in2[TILE];

    const int e    = blockIdx.y;
    const int cnt  = counts[e * CSTRIDE];
    const int base = blockIdx.x * TILE;
    if (base >= cnt) return;
    const int ns = min(TILE, cnt - base);
    const int tid = threadIdx.x;
    const int sg  = tid >> 5;
    const int cg  = tid & 31;

    if (tid < TILE) sidx[tid] = buckets[e * B_N + base + ((tid < ns) ? tid : 0)];
    __syncthreads();

    float acc[8][12];
#pragma unroll
    for (int i = 0; i < 8; ++i)
#pragma unroll
        for (int j = 0; j < 12; ++j) acc[i][j] = 0.f;

    const float* W1e = W1 + (size_t)e * H_DIM * HH;
    const int r = tid >> 2, q = tid & 3;
    const float* xrow = emb + (size_t)sidx[r] * H_DIM;

    for (int kk = 0; kk < H_DIM; kk += BK) {
#pragma unroll
        for (int i = 0; i < 4; ++i)
            *reinterpret_cast<float4*>(&Xs[r][q * 16 + i * 4]) =
                *reinterpret_cast<const float4*>(xrow + kk + q * 16 + i * 4);
        __syncthreads();
#pragma unroll 2
        for (int k = 0; k < BK; ++k) {
            float xv[8], wv[12];
            const float* wrow = W1e + (size_t)(kk + k) * HH + cg;
#pragma unroll
            for (int j = 0; j < 12; ++j) wv[j] = wrow[j * 32];
#pragma unroll
            for (int i = 0; i < 8; ++i) xv[i] = Xs[sg * 8 + i][k];
#pragma unroll
            for (int i = 0; i < 8; ++i)
#pragma unroll
                for (int j = 0; j < 12; ++j) acc[i][j] = fmaf(xv[i], wv[j], acc[i][j]);
        }
        __syncthreads();
    }
    const float* b1e = b1 + e * HH;
#pragma unroll
    for (int j = 0; j < 12; ++j) {
        float bb = b1e[cg + j * 32];
#pragma unroll
        for (int i = 0; i < 8; ++i)
            Hs[sg * 8 + i][cg + j * 32] = __float2bfloat16(fmaxf(acc[i][j] + bb, 0.f));
    }
    __syncthreads();

    const float* W2e = W2 + (size_t)e * HH * H_DIM;
    const float* b2e = b2 + e * H_DIM;
    float S1[8], S2[8], S3[8];
#pragma unroll
    for (int i = 0; i < 8; ++i) { S1[i] = 0.f; S2[i] = 0.f; S3[i] = 0.f; }

    for (int hb = 0; hb < H_DIM; hb += 384) {
        float acc2[8][12];
#pragma unroll
        for (int i = 0; i < 8; ++i)
#pragma unroll
            for (int j = 0; j < 12; ++j) acc2[i][j] = 0.f;
#pragma unroll 2
        for (int k = 0; k < HH; ++k) {
            float hv[8], wv[12];
            const float* wrow = W2e + (size_t)k * H_DIM + hb + cg;
#pragma unroll
            for (int j = 0; j < 12; ++j) wv[j] = wrow[j * 32];
#pragma unroll
            for (int i = 0; i < 8; ++i) hv[i] = __bfloat162float(Hs[sg * 8 + i][k]);
#pragma unroll
            for (int i = 0; i < 8; ++i)
#pragma unroll
                for (int j = 0; j < 12; ++j) acc2[i][j] = fmaf(hv[i], wv[j], acc2[i][j]);
        }
#pragma unroll
        for (int j = 0; j < 12; ++j) {
            int col = hb + cg + j * 32;
            float bb = b2e[col];
#pragma unroll
            for (int i = 0; i < 8; ++i) {
                int s = sg * 8 + i;
                float y = acc2[i][j] + bb;
                size_t o = (size_t)sidx[s] * H_DIM + col;
                float x = emb[o];
                S1[i] = fmaf(y, y, S1[i]);
                S2[i] = fmaf(y, x, S2[i]);
                S3[i] = fmaf(x, x, S3[i]);
                if (s < ns) out[o] = y;
            }
        }
    }
#pragma unroll
    for (int i = 0; i < 8; ++i) {
        float v1 = S1[i], v2 = S2[i], v3 = S3[i];
#pragma unroll
        for (int m = 1; m < 32; m <<= 1) {
            v1 += __shfl_xor(v1, m); v2 += __shfl_xor(v2, m); v3 += __shfl_xor(v3, m);
        }
        if (cg == 0) {
            float n1 = fmaxf(sqrtf(v1), 1e-6f);
            float t  = v1 / (n1 * n1) + 2.f * v2 / n1 + v3;
            s_in1[sg * 8 + i] = 1.f / n1;
            s_in2[sg * 8 + i] = 1.f / fmaxf(sqrtf(t), 1e-12f);
        }
    }
    __syncthreads();
#pragma unroll
    for (int i = 0; i < 8; ++i) {
        int s = sg * 8 + i;
        if (s >= ns) continue;
        float in1 = s_in1[s], in2 = s_in2[s];
        size_t rowo = (size_t)sidx[s] * H_DIM;
#pragma unroll
        for (int j = 0; j < 24; ++j) {
            int col = cg + j * 32;
            out[rowo + col] = (out[rowo + col] * in1 + emb[rowo + col]) * in2;
        }
    }
}

// ---------------- launch ----------------
extern "C" void kernel_launch(void* const* d_in, const int* in_sizes, int n_in,
                              void* d_out, int out_size, void* d_ws, size_t ws_size,
                              hipStream_t stream) {
    const float* emb    = (const float*)d_in[0];
    const float* logits = (const float*)d_in[1];
    const float* W1     = (const float*)d_in[2];
    const float* b1     = (const float*)d_in[3];
    const float* W2     = (const float*)d_in[4];
    const float* b2     = (const float*)d_in[5];
    float* out = (float*)d_out;

    int* counts  = (int*)d_ws;                              // 8 counters, 128B apart (1KB)
    int* buckets = (int*)((char*)d_ws + 1024);              // [8][16384] int (512KB)
    unsigned short* W1T = (unsigned short*)((char*)d_ws + 1024 + 524288);
    unsigned short* W2T = W1T + (size_t)NE * HH * H_DIM;    // each 4.72MB
    unsigned short* Hws = W2T + (size_t)NE * HH * H_DIM;    // 12.6MB
    const size_t needed = 1024 + 524288
                        + 2 * (size_t)NE * HH * H_DIM * sizeof(unsigned short)
                        + (size_t)B_N * HH * sizeof(unsigned short);

    if (ws_size >= needed) {
        transpose_cvt_kernel<<<dim3(288, NE, 2), 256, 0, stream>>>(W1, W2, W1T, W2T, counts);
        route_kernel<<<B_N / 256, 256, 0, stream>>>(logits, counts, buckets);
        gemm_kernel<H_DIM, HH, true, true, true>
            <<<NE * 256 * 3, 512, 0, stream>>>(emb, W1T, b1, counts, buckets, Hws);
        gemm2n_kernel<<<NE * 256, 512, 0, stream>>>(Hws, W2T, b2, emb, counts, buckets, out);
    } else {
        zero_counts_kernel<<<1, 64, 0, stream>>>(counts);
        route_kernel<<<B_N / 256, 256, 0, stream>>>(logits, counts, buckets);
        moe_fused_fallback<<<dim3(B_N / TILE, NE), NTHR, 0, stream>>>(
            emb, W1, b1, W2, b2, counts, buckets, out);
    }
}